// Round 9
// baseline (123.861 us; speedup 1.0000x reference)
//
#include <hip/hip_runtime.h>

#define IC 3
#define OCH 16
#define IDD 16
#define IHH 32
#define IWW 32
#define ODD 31
#define OHH 63
#define OWW 63
#define NB 32

typedef float f2 __attribute__((ext_vector_type(2)));
typedef float f4 __attribute__((ext_vector_type(4)));

#define LOG2E 1.44269504088896340736f
#define LN2   0.69314718055994530942f

static __device__ __forceinline__ f2 fma2(f2 a, f2 b, f2 c) {
    return __builtin_elementwise_fma(a, b, c);   // -> v_pk_fma_f32
}
static __device__ __forceinline__ f2 bc(float s) { f2 r; r.x = s; r.y = s; return r; }

// ---- kernel A: one-time weight transpose into workspace -------------------------
// wt[((ic*3+kd)*9 + kh*3+kw)*16 + oc] = w[(ic*16+oc)*27 + kd*9+kh*3+kw] * log2(e)
__global__ void wprep_kernel(const float* __restrict__ w, float* __restrict__ wt) {
    int idx = threadIdx.x + blockIdx.x * 256;
    if (idx < IC * 27 * OCH) {
        int ic   = idx / (27 * OCH);
        int rem  = idx - ic * (27 * OCH);
        int kpos = rem >> 4;
        int oc   = rem & 15;
        wt[idx] = w[(ic * OCH + oc) * 27 + kpos] * LOG2E;
    }
}

// ---- main kernel ----------------------------------------------------------------
// Fused ConvTranspose3d(3->16,k3,s2,p1) + channel-LSE + x*sigmoid(x+3)/6 - bias, clip [-1,1].
// Round-8 base (no LDS, no barrier, wave-broadcast global weight f4s, packed-f2 FMAs,
// straight-line single phase). NEW: oc-split pixel-doubling -- lane pairs (tid&1) split the
// 16 channels, each lane covers 8 oc of the SAME 8 pixels (2 ow-pairs x 1 oh-pair):
// per-thread FMA count unchanged, weight-load instruction count HALVED, finish work halved.
// LSE halves merged via 8x __shfl_xor(ss,1) (sum-of-exp is additive; no max-sub needed).
// acc = 8px x 4 f2 = 64 floats (proven-safe size); all array indices compile-time.
__global__ __launch_bounds__(256, 4) void convt_lse_kernel(
    const float* __restrict__ x, const float* __restrict__ wt,
    const float* __restrict__ bias, float* __restrict__ out)
{
    const int h  = threadIdx.x & 1;                          // oc half: 0 -> oc0-7, 1 -> oc8-15
    const int jj = (threadIdx.x >> 1) & 15;                  // ow quad: ow = 4jj .. 4jj+3
    const int i  = (threadIdx.x >> 5) + (blockIdx.x << 3);   // oh pair: oh = 2i, 2i+1
    const int od = blockIdx.y;
    const int b  = blockIdx.z;

    const int r0 = i * IWW;
    const int r1 = min(i + 1, IHH - 1) * IWW;  // clamp: feeds only non-stored oh=63
    const int c0 = 2 * jj;
    const int c1 = 2 * jj + 1;
    const int c2 = min(2 * jj + 2, IWW - 1);   // clamp: feeds only non-stored ow=63

    const bool odd = (od & 1) != 0;
    const int id0 = odd ? ((od + 1) >> 1) : (od >> 1);
    const int id1 = (od - 1) >> 1;             // used only when odd

    const float bv = bias[0];

    // acc[px][cp]: px 0-3 = pair A (ee,eo,oe,oo), 4-7 = pair B; cp = f2 oc-pair in this half
    f2 acc[8][4];

// One (ic,kd) tap-plane: 18 f4 weight loads (9 taps x 2 quads of this oc-half),
// 72 pk-fma covering both ow-pairs. Wave issues 2 distinct weight addrs (h=0/1) -> 2 L1 lines.
#define EMIT(first, X00, X01, X02, X10, X11, X12, wq)                                 \
    {                                                                                 \
        _Pragma("unroll")                                                             \
        for (int s = 0; s < 2; ++s) {                                                 \
            const f4 W0 = wq[0 + s],  W1 = wq[4 + s],  W2 = wq[8 + s],                \
                     W3 = wq[12 + s], W4 = wq[16 + s], W5 = wq[20 + s],               \
                     W6 = wq[24 + s], W7 = wq[28 + s], W8 = wq[32 + s];               \
            _Pragma("unroll")                                                         \
            for (int h2 = 0; h2 < 2; ++h2) {                                          \
                const int cp = s * 2 + h2;                                            \
                const f2 w0 = {W0[2*h2], W0[2*h2+1]}, w1 = {W1[2*h2], W1[2*h2+1]},    \
                         w2 = {W2[2*h2], W2[2*h2+1]}, w3 = {W3[2*h2], W3[2*h2+1]},    \
                         w4 = {W4[2*h2], W4[2*h2+1]}, w5 = {W5[2*h2], W5[2*h2+1]},    \
                         w6 = {W6[2*h2], W6[2*h2+1]}, w7 = {W7[2*h2], W7[2*h2+1]},    \
                         w8 = {W8[2*h2], W8[2*h2+1]};                                 \
                if (first) {                                                          \
                    acc[0][cp] = X00 * w4;  acc[4][cp] = X01 * w4;                    \
                    acc[1][cp] = X01 * w3;  acc[5][cp] = X02 * w3;                    \
                    acc[2][cp] = X10 * w1;  acc[6][cp] = X11 * w1;                    \
                    acc[3][cp] = X11 * w0;  acc[7][cp] = X12 * w0;                    \
                } else {                                                              \
                    acc[0][cp] = fma2(X00, w4, acc[0][cp]);                           \
                    acc[4][cp] = fma2(X01, w4, acc[4][cp]);                           \
                    acc[1][cp] = fma2(X01, w3, acc[1][cp]);                           \
                    acc[5][cp] = fma2(X02, w3, acc[5][cp]);                           \
                    acc[2][cp] = fma2(X10, w1, acc[2][cp]);                           \
                    acc[6][cp] = fma2(X11, w1, acc[6][cp]);                           \
                    acc[3][cp] = fma2(X11, w0, acc[3][cp]);                           \
                    acc[7][cp] = fma2(X12, w0, acc[7][cp]);                           \
                }                                                                     \
                acc[1][cp] = fma2(X00, w5, acc[1][cp]);                               \
                acc[5][cp] = fma2(X01, w5, acc[5][cp]);                               \
                acc[2][cp] = fma2(X00, w7, acc[2][cp]);                               \
                acc[6][cp] = fma2(X01, w7, acc[6][cp]);                               \
                acc[3][cp] = fma2(X10, w2, acc[3][cp]);                               \
                acc[7][cp] = fma2(X11, w2, acc[7][cp]);                               \
                acc[3][cp] = fma2(X01, w6, acc[3][cp]);                               \
                acc[7][cp] = fma2(X02, w6, acc[7][cp]);                               \
                acc[3][cp] = fma2(X00, w8, acc[3][cp]);                               \
                acc[7][cp] = fma2(X01, w8, acc[7][cp]);                               \
            }                                                                         \
        }                                                                             \
    }

#define DO_IC(ic, kd, id, first)                                                      \
    {                                                                                 \
        const float* __restrict__ xp = x + ((((b) * IC + (ic)) * IDD + (id)) << 10);  \
        const f2 X00 = bc(xp[r0 + c0]), X01 = bc(xp[r0 + c1]), X02 = bc(xp[r0 + c2]); \
        const f2 X10 = bc(xp[r1 + c0]), X11 = bc(xp[r1 + c1]), X12 = bc(xp[r1 + c2]); \
        const f4* __restrict__ wq = (const f4*)(wt + ((ic) * 3 + (kd)) * 9 * OCH + h * 8); \
        EMIT(first, X00, X01, X02, X10, X11, X12, wq)                                 \
    }

    if (odd) {          // odd od: kd=0 @ id0=(od+1)/2, kd=2 @ id1=(od-1)/2
        DO_IC(0, 0, id0, true)
        DO_IC(1, 0, id0, false)
        DO_IC(2, 0, id0, false)
        DO_IC(0, 2, id1, false)
        DO_IC(1, 2, id1, false)
        DO_IC(2, 2, id1, false)
    } else {            // even od: kd=1 @ id0=od/2
        DO_IC(0, 1, id0, true)
        DO_IC(1, 1, id0, false)
        DO_IC(2, 1, id0, false)
    }

    // per-pixel sum of exp2 over this lane's 8 oc (log2-domain acc; no max-sub)
    float ss[8];
    #pragma unroll
    for (int px = 0; px < 8; ++px) {
        f2 e0, e1, e2, e3;
        e0.x = __builtin_amdgcn_exp2f(acc[px][0].x);
        e0.y = __builtin_amdgcn_exp2f(acc[px][0].y);
        e1.x = __builtin_amdgcn_exp2f(acc[px][1].x);
        e1.y = __builtin_amdgcn_exp2f(acc[px][1].y);
        e2.x = __builtin_amdgcn_exp2f(acc[px][2].x);
        e2.y = __builtin_amdgcn_exp2f(acc[px][2].y);
        e3.x = __builtin_amdgcn_exp2f(acc[px][3].x);
        e3.y = __builtin_amdgcn_exp2f(acc[px][3].y);
        const f2 t = (e0 + e1) + (e2 + e3);
        ss[px] = t.x + t.y;
    }

    // merge oc-halves across the lane pair (both lanes end with full sums)
    float Sv[8];
    #pragma unroll
    for (int px = 0; px < 8; ++px) Sv[px] = ss[px] + __shfl_xor(ss[px], 1);

    // this lane finishes its own ow-pair: h=0 -> pair A (ow 4jj,4jj+1), h=1 -> pair B (+2)
    const int oh0   = 2 * i;
    const int owb   = 4 * jj + 2 * h;
    const int obase = (b * ODD + od) * OHH;

    #pragma unroll
    for (int r = 0; r < 2; ++r) {
        const int oh = oh0 + r;
        if (oh < OHH) {
            #pragma unroll
            for (int c = 0; c < 2; ++c) {
                const int ow = owb + c;
                if (ow < OWW) {
                    // compile-time indices in both arms (rule #20: no runtime array index)
                    const float S = h ? Sv[4 + 2 * r + c] : Sv[2 * r + c];
                    const float v = LN2 * __builtin_amdgcn_logf(S);          // ln(S)
                    const float t   = __builtin_amdgcn_exp2f(fmaf(-LOG2E, v, -3.0f * LOG2E));
                    const float den = fmaf(6.0f, t, 6.0f);
                    const float hs  = v * __builtin_amdgcn_rcpf(den);
                    const float rr  = fminf(1.0f, fmaxf(-1.0f, hs - bv));
                    out[(obase + oh) * OWW + ow] = rr;
                }
            }
        }
    }
}

extern "C" void kernel_launch(void* const* d_in, const int* in_sizes, int n_in,
                              void* d_out, int out_size, void* d_ws, size_t ws_size,
                              hipStream_t stream) {
    const float* x    = (const float*)d_in[0];
    const float* w    = (const float*)d_in[1];
    const float* bias = (const float*)d_in[2];
    float* out        = (float*)d_out;
    float* wt         = (float*)d_ws;     // 1296 floats = 5.2 KB scratch

    wprep_kernel<<<dim3(6), dim3(256), 0, stream>>>(w, wt);

    dim3 grid(4, ODD, NB);   // 4 i-chunks (8 i-values each) x od x batch
    dim3 block(256);
    convt_lse_kernel<<<grid, block, 0, stream>>>(x, wt, bias, out);
}

// Round 10
// 122.437 us; speedup vs baseline: 1.0116x; 1.0116x over previous
//
#include <hip/hip_runtime.h>

#define IC 3
#define OCH 16
#define IDD 16
#define IHH 32
#define IWW 32
#define ODD 31
#define OHH 63
#define OWW 63
#define NB 32

typedef float f2 __attribute__((ext_vector_type(2)));
typedef float f4 __attribute__((ext_vector_type(4)));

#define LOG2E 1.44269504088896340736f
#define LN2   0.69314718055994530942f

static __device__ __forceinline__ f2 fma2(f2 a, f2 b, f2 c) {
    return __builtin_elementwise_fma(a, b, c);   // -> v_pk_fma_f32
}
static __device__ __forceinline__ f2 bc(float s) { f2 r; r.x = s; r.y = s; return r; }

// ---- kernel A: one-time weight transpose into workspace -------------------------
// wt[((ic*3+kd)*9 + kh*3+kw)*16 + oc] = w[(ic*16+oc)*27 + kd*9+kh*3+kw] * log2(e)
__global__ void wprep_kernel(const float* __restrict__ w, float* __restrict__ wt) {
    int idx = threadIdx.x + blockIdx.x * 256;
    if (idx < IC * 27 * OCH) {
        int ic   = idx / (27 * OCH);
        int rem  = idx - ic * (27 * OCH);
        int kpos = rem >> 4;
        int oc   = rem & 15;
        wt[idx] = w[(ic * OCH + oc) * 27 + kpos] * LOG2E;
    }
}

// ---- main kernel ----------------------------------------------------------------
// Fused ConvTranspose3d(3->16,k3,s2,p1) + channel-LSE + x*sigmoid(x+3)/6 - bias, clip [-1,1].
// Round-8 base (no LDS/barrier, wave-broadcast global weight f4s, packed-f2 FMAs, one
// straight-line phase) + oc-split pixel-doubling (lane pairs split the 16 channels; each lane
// covers 8 oc of the SAME 8 pixels): weight-load instructions halved (54/108 per thread),
// finish work halved, FMA count unchanged. ROUND-9 SPILL FIX: weights are loaded PER-TAP
// (2 f4 live at a time, not 9) so source-level peak pressure is ~95 VGPR, well under the
// __launch_bounds__(256,4) 128 cap. LSE halves merged via __shfl_xor(ss,1).
__global__ __launch_bounds__(256, 4) void convt_lse_kernel(
    const float* __restrict__ x, const float* __restrict__ wt,
    const float* __restrict__ bias, float* __restrict__ out)
{
    const int h  = threadIdx.x & 1;                          // oc half: 0 -> oc0-7, 1 -> oc8-15
    const int jj = (threadIdx.x >> 1) & 15;                  // ow quad: ow = 4jj .. 4jj+3
    const int i  = (threadIdx.x >> 5) + (blockIdx.x << 3);   // oh pair: oh = 2i, 2i+1
    const int od = blockIdx.y;
    const int b  = blockIdx.z;

    const int r0 = i * IWW;
    const int r1 = min(i + 1, IHH - 1) * IWW;  // clamp: feeds only non-stored oh=63
    const int c0 = 2 * jj;
    const int c1 = 2 * jj + 1;
    const int c2 = min(2 * jj + 2, IWW - 1);   // clamp: feeds only non-stored ow=63

    const bool odd = (od & 1) != 0;
    const int id0 = odd ? ((od + 1) >> 1) : (od >> 1);
    const int id1 = (od - 1) >> 1;             // used only when odd

    const float bv = bias[0];

    // acc[px][cp]: px 0-3 = pair A parities (ee,eo,oe,oo), 4-7 = pair B; cp = f2 oc-pair
    f2 acc[8][4];

// One (kh,kw) tap m with parity class p: load this half's 2 f4 (8 oc), 8 pk-FMA
// (pair A gets XA, pair B gets XB). Live weight regs: 8 floats only.
#define TAP1(m, p, first, XA, XB)                                                     \
    {                                                                                 \
        const f4 Wa = wq[(m) * 4 + 0], Wb = wq[(m) * 4 + 1];                          \
        const f2 wa0 = {Wa[0], Wa[1]}, wa1 = {Wa[2], Wa[3]},                          \
                 wb0 = {Wb[0], Wb[1]}, wb1 = {Wb[2], Wb[3]};                          \
        if (first) {                                                                  \
            acc[p][0]     = (XA) * wa0;  acc[p][1]     = (XA) * wa1;                  \
            acc[p][2]     = (XA) * wb0;  acc[p][3]     = (XA) * wb1;                  \
            acc[4 + p][0] = (XB) * wa0;  acc[4 + p][1] = (XB) * wa1;                  \
            acc[4 + p][2] = (XB) * wb0;  acc[4 + p][3] = (XB) * wb1;                  \
        } else {                                                                      \
            acc[p][0]     = fma2((XA), wa0, acc[p][0]);                               \
            acc[p][1]     = fma2((XA), wa1, acc[p][1]);                               \
            acc[p][2]     = fma2((XA), wb0, acc[p][2]);                               \
            acc[p][3]     = fma2((XA), wb1, acc[p][3]);                               \
            acc[4 + p][0] = fma2((XB), wa0, acc[4 + p][0]);                           \
            acc[4 + p][1] = fma2((XB), wa1, acc[4 + p][1]);                           \
            acc[4 + p][2] = fma2((XB), wb0, acc[4 + p][2]);                           \
            acc[4 + p][3] = fma2((XB), wb1, acc[4 + p][3]);                           \
        }                                                                             \
    }

// One (ic,kd) plane: 6 x-broadcasts, 9 taps (init taps first per parity when 'first').
// Tap->parity / x mapping identical to round-8/9's proven EMIT.
#define DO_IC(ic, kd, id, first)                                                      \
    {                                                                                 \
        const float* __restrict__ xp = x + ((((b) * IC + (ic)) * IDD + (id)) << 10);  \
        const f2 X00 = bc(xp[r0 + c0]), X01 = bc(xp[r0 + c1]), X02 = bc(xp[r0 + c2]); \
        const f2 X10 = bc(xp[r1 + c0]), X11 = bc(xp[r1 + c1]), X12 = bc(xp[r1 + c2]); \
        const f4* __restrict__ wq =                                                   \
            (const f4*)(wt + ((ic) * 3 + (kd)) * 9 * OCH) + h * 2;                    \
        TAP1(4, 0, first, X00, X01)   /* kh=1,kw=1 -> (ee) */                         \
        TAP1(3, 1, first, X01, X02)   /* kh=1,kw=0 -> (eo) init */                    \
        TAP1(5, 1, false, X00, X01)   /* kh=1,kw=2 -> (eo) */                         \
        TAP1(1, 2, first, X10, X11)   /* kh=0,kw=1 -> (oe) init */                    \
        TAP1(7, 2, false, X00, X01)   /* kh=2,kw=1 -> (oe) */                         \
        TAP1(0, 3, first, X11, X12)   /* kh=0,kw=0 -> (oo) init */                    \
        TAP1(2, 3, false, X10, X11)   /* kh=0,kw=2 -> (oo) */                         \
        TAP1(6, 3, false, X01, X02)   /* kh=2,kw=0 -> (oo) */                         \
        TAP1(8, 3, false, X00, X01)   /* kh=2,kw=2 -> (oo) */                         \
    }

    if (odd) {          // odd od: kd=0 @ id0=(od+1)/2, kd=2 @ id1=(od-1)/2
        DO_IC(0, 0, id0, true)
        DO_IC(1, 0, id0, false)
        DO_IC(2, 0, id0, false)
        DO_IC(0, 2, id1, false)
        DO_IC(1, 2, id1, false)
        DO_IC(2, 2, id1, false)
    } else {            // even od: kd=1 @ id0=od/2
        DO_IC(0, 1, id0, true)
        DO_IC(1, 1, id0, false)
        DO_IC(2, 1, id0, false)
    }

    // per-pixel sum of exp2 over this lane's 8 oc (log2-domain acc; no max-sub)
    float ss[8];
    #pragma unroll
    for (int px = 0; px < 8; ++px) {
        f2 e0, e1, e2, e3;
        e0.x = __builtin_amdgcn_exp2f(acc[px][0].x);
        e0.y = __builtin_amdgcn_exp2f(acc[px][0].y);
        e1.x = __builtin_amdgcn_exp2f(acc[px][1].x);
        e1.y = __builtin_amdgcn_exp2f(acc[px][1].y);
        e2.x = __builtin_amdgcn_exp2f(acc[px][2].x);
        e2.y = __builtin_amdgcn_exp2f(acc[px][2].y);
        e3.x = __builtin_amdgcn_exp2f(acc[px][3].x);
        e3.y = __builtin_amdgcn_exp2f(acc[px][3].y);
        const f2 t = (e0 + e1) + (e2 + e3);
        ss[px] = t.x + t.y;
    }

    // merge oc-halves across the lane pair (both lanes end with full sums)
    float Sv[8];
    #pragma unroll
    for (int px = 0; px < 8; ++px) Sv[px] = ss[px] + __shfl_xor(ss[px], 1);

    // this lane finishes its own ow-pair: h=0 -> pair A (ow 4jj,4jj+1), h=1 -> pair B (+2)
    const int oh0   = 2 * i;
    const int owb   = 4 * jj + 2 * h;
    const int obase = (b * ODD + od) * OHH;

    #pragma unroll
    for (int r = 0; r < 2; ++r) {
        const int oh = oh0 + r;
        if (oh < OHH) {
            #pragma unroll
            for (int c = 0; c < 2; ++c) {
                const int ow = owb + c;
                if (ow < OWW) {
                    // compile-time indices in both arms (rule #20)
                    const float S = h ? Sv[4 + 2 * r + c] : Sv[2 * r + c];
                    const float v = LN2 * __builtin_amdgcn_logf(S);          // ln(S)
                    const float t   = __builtin_amdgcn_exp2f(fmaf(-LOG2E, v, -3.0f * LOG2E));
                    const float den = fmaf(6.0f, t, 6.0f);
                    const float hs  = v * __builtin_amdgcn_rcpf(den);
                    const float rr  = fminf(1.0f, fmaxf(-1.0f, hs - bv));
                    out[(obase + oh) * OWW + ow] = rr;
                }
            }
        }
    }
}

extern "C" void kernel_launch(void* const* d_in, const int* in_sizes, int n_in,
                              void* d_out, int out_size, void* d_ws, size_t ws_size,
                              hipStream_t stream) {
    const float* x    = (const float*)d_in[0];
    const float* w    = (const float*)d_in[1];
    const float* bias = (const float*)d_in[2];
    float* out        = (float*)d_out;
    float* wt         = (float*)d_ws;     // 1296 floats = 5.2 KB scratch

    wprep_kernel<<<dim3(6), dim3(256), 0, stream>>>(w, wt);

    dim3 grid(4, ODD, NB);   // 4 i-chunks (8 i-values each) x od x batch
    dim3 block(256);
    convt_lse_kernel<<<grid, block, 0, stream>>>(x, wt, bias, out);
}

// Round 11
// 98.508 us; speedup vs baseline: 1.2574x; 1.2429x over previous
//
#include <hip/hip_runtime.h>

#define IC 3
#define OCH 16
#define IDD 16
#define IHH 32
#define IWW 32
#define ODD 31
#define OHH 63
#define OWW 63
#define NB 32

typedef float f2 __attribute__((ext_vector_type(2)));
typedef float f4 __attribute__((ext_vector_type(4)));

#define LOG2E 1.44269504088896340736f
#define LN2   0.69314718055994530942f

static __device__ __forceinline__ f2 fma2(f2 a, f2 b, f2 c) {
    return __builtin_elementwise_fma(a, b, c);   // -> v_pk_fma_f32
}

// ---- kernel A: one-time weight transpose into workspace -------------------------
// wt[((ic*3+kd)*9 + kh*3+kw)*16 + oc] = w[(ic*16+oc)*27 + kd*9+kh*3+kw] * log2(e)
__global__ void wprep_kernel(const float* __restrict__ w, float* __restrict__ wt) {
    int idx = threadIdx.x + blockIdx.x * 256;
    if (idx < IC * 27 * OCH) {
        int ic   = idx / (27 * OCH);
        int rem  = idx - ic * (27 * OCH);
        int kpos = rem >> 4;
        int oc   = rem & 15;
        wt[idx] = w[(ic * OCH + oc) * 27 + kpos] * LOG2E;
    }
}

// ---- main kernel ----------------------------------------------------------------
// Fused ConvTranspose3d(3->16,k3,s2,p1) + channel-LSE + x*sigmoid(x+3)/6 - bias, clip [-1,1].
// Round-8's proven shape (2x2 patch/thread, one od, packed-f2 acc, straight-line single
// phase, NO __syncthreads). SINGLE DELTA vs round-8: weights come from LDS again, but staged
// BARRIER-FREE -- every wave redundantly copies the whole 5.2 KB table (6 f4 loads + 6
// ds_writes per lane; same-value races across waves are benign; the wave's own lgkmcnt
// guarantees visibility of all 64 lanes' writes). Weight reads (ds_read_b128, ~60cyc) now
// wait on lgkmcnt while x loads wait on vmcnt -> decoupled load streams, no barrier convoy.
__global__ __launch_bounds__(256, 4) void convt_lse_kernel(
    const float* __restrict__ x, const float* __restrict__ wt,
    const float* __restrict__ bias, float* __restrict__ out)
{
    __shared__ __align__(16) float wl[IC * 27 * OCH];   // 1296 floats = 324 f4

    // per-WAVE redundant staging: no cross-wave dependency, no __syncthreads
    {
        const int lane = threadIdx.x & 63;
        const f4* __restrict__ src = (const f4*)wt;
        f4* __restrict__ dst = (f4*)wl;
        for (int idx = lane; idx < IC * 27 * OCH / 4; idx += 64)
            dst[idx] = src[idx];
    }

    const int j  = threadIdx.x & 31;                       // ow pair: ow = 2j, 2j+1
    const int i  = (threadIdx.x >> 5) + (blockIdx.x << 3); // oh pair: oh = 2i, 2i+1
    const int od = blockIdx.y;
    const int b  = blockIdx.z;

    const int ih0 = i;
    const int ih1 = min(i + 1, IHH - 1);   // clamp: feeds only non-stored oh=63
    const int iw0 = j;
    const int iw1 = min(j + 1, IWW - 1);   // clamp: feeds only non-stored ow=63

    const bool odd = (od & 1) != 0;
    const int id0 = odd ? ((od + 1) >> 1) : (od >> 1);
    const int id1 = (od - 1) >> 1;         // used only when odd

    // x loads issued early; their vmcnt waits land inside the FMA stream
    float xr[2][IC][4];    // [tap][ic][{00,01,10,11}] - compile-time indexed only
    #pragma unroll
    for (int ic = 0; ic < IC; ++ic) {
        const float* __restrict__ xp = x + (((b * IC + ic) * IDD + id0) << 10);
        xr[0][ic][0] = xp[ih0 * IWW + iw0];
        xr[0][ic][1] = xp[ih0 * IWW + iw1];
        xr[0][ic][2] = xp[ih1 * IWW + iw0];
        xr[0][ic][3] = xp[ih1 * IWW + iw1];
    }
    if (odd) {
        #pragma unroll
        for (int ic = 0; ic < IC; ++ic) {
            const float* __restrict__ xp = x + (((b * IC + ic) * IDD + id1) << 10);
            xr[1][ic][0] = xp[ih0 * IWW + iw0];
            xr[1][ic][1] = xp[ih0 * IWW + iw1];
            xr[1][ic][2] = xp[ih1 * IWW + iw0];
            xr[1][ic][3] = xp[ih1 * IWW + iw1];
        }
    }
    const float bv = bias[0];

    // acc[p][cp]: p 0=(ee) 1=(eo) 2=(oe) 3=(oo); cp = oc pair (2 channels)
    f2 acc[4][8];

// 9 f4 weight loads per q-group (uniform LDS addr -> broadcast ds_read_b128, conflict-free)
// feeding 18 pk-fma per (ic,q)
#define TAPQ(first, x00, x01, x10, x11, wq)                                           \
    {                                                                                 \
        _Pragma("unroll")                                                             \
        for (int q = 0; q < 4; ++q) {                                                 \
            const f4 W0 = wq[0 * 4 + q], W1 = wq[1 * 4 + q], W2 = wq[2 * 4 + q],      \
                     W3 = wq[3 * 4 + q], W4 = wq[4 * 4 + q], W5 = wq[5 * 4 + q],      \
                     W6 = wq[6 * 4 + q], W7 = wq[7 * 4 + q], W8 = wq[8 * 4 + q];      \
            _Pragma("unroll")                                                         \
            for (int h = 0; h < 2; ++h) {                                             \
                const int cp = 2 * q + h;                                             \
                const f2 w0 = {W0[2*h], W0[2*h+1]}, w1 = {W1[2*h], W1[2*h+1]},        \
                         w2 = {W2[2*h], W2[2*h+1]}, w3 = {W3[2*h], W3[2*h+1]},        \
                         w4 = {W4[2*h], W4[2*h+1]}, w5 = {W5[2*h], W5[2*h+1]},        \
                         w6 = {W6[2*h], W6[2*h+1]}, w7 = {W7[2*h], W7[2*h+1]},        \
                         w8 = {W8[2*h], W8[2*h+1]};                                   \
                if (first) {                                                          \
                    acc[3][cp] = x11 * w0;                                            \
                    acc[2][cp] = x10 * w1;                                            \
                    acc[1][cp] = x01 * w3;                                            \
                    acc[0][cp] = x00 * w4;                                            \
                } else {                                                              \
                    acc[3][cp] = fma2(x11, w0, acc[3][cp]);                           \
                    acc[2][cp] = fma2(x10, w1, acc[2][cp]);                           \
                    acc[1][cp] = fma2(x01, w3, acc[1][cp]);                           \
                    acc[0][cp] = fma2(x00, w4, acc[0][cp]);                           \
                }                                                                     \
                acc[3][cp] = fma2(x10, w2, acc[3][cp]);                               \
                acc[1][cp] = fma2(x00, w5, acc[1][cp]);                               \
                acc[3][cp] = fma2(x01, w6, acc[3][cp]);                               \
                acc[2][cp] = fma2(x00, w7, acc[2][cp]);                               \
                acc[3][cp] = fma2(x00, w8, acc[3][cp]);                               \
            }                                                                         \
        }                                                                             \
    }

#define DO_TAP(kd, tpi, first)                                                        \
    {                                                                                 \
        _Pragma("unroll")                                                             \
        for (int ic = 0; ic < IC; ++ic) {                                             \
            const f2 x00 = {xr[tpi][ic][0], xr[tpi][ic][0]};                          \
            const f2 x01 = {xr[tpi][ic][1], xr[tpi][ic][1]};                          \
            const f2 x10 = {xr[tpi][ic][2], xr[tpi][ic][2]};                          \
            const f2 x11 = {xr[tpi][ic][3], xr[tpi][ic][3]};                          \
            const f4* __restrict__ wq = (const f4*)(wl + (ic * 3 + (kd)) * 9 * OCH);  \
            TAPQ((first) && ic == 0, x00, x01, x10, x11, wq)                          \
        }                                                                             \
    }

    if (odd) {          // odd od: kd=0 @ id0=(od+1)/2, kd=2 @ id1=(od-1)/2
        DO_TAP(0, 0, true)
        DO_TAP(2, 1, false)
    } else {            // even od: kd=1 @ id0=od/2
        DO_TAP(1, 0, true)
    }

    const int oh0   = 2 * i;
    const int ow0   = 2 * j;
    const int obase = (b * ODD + od) * OHH;

    #pragma unroll
    for (int p = 0; p < 4; ++p) {
        const int oh = oh0 + (p >> 1);
        const int ow = ow0 + (p & 1);
        if (oh < OHH && ow < OWW) {
            // acc is log2-domain: S = sum exp2(acc); no max-sub (|acc| bounded << 126)
            f2 sa = {0.0f, 0.0f}, sb = {0.0f, 0.0f};
            #pragma unroll
            for (int cp = 0; cp < 8; cp += 2) {
                f2 ea, eb;
                ea.x = __builtin_amdgcn_exp2f(acc[p][cp].x);
                ea.y = __builtin_amdgcn_exp2f(acc[p][cp].y);
                eb.x = __builtin_amdgcn_exp2f(acc[p][cp + 1].x);
                eb.y = __builtin_amdgcn_exp2f(acc[p][cp + 1].y);
                sa += ea;                       // v_pk_add_f32
                sb += eb;
            }
            const f2 st   = sa + sb;
            const float S = st.x + st.y;
            const float v = LN2 * __builtin_amdgcn_logf(S);          // ln(S)
            // v / (6*(1+exp(-(v+3)))), exp via exp2(fma), fast rcp
            const float t   = __builtin_amdgcn_exp2f(fmaf(-LOG2E, v, -3.0f * LOG2E));
            const float den = fmaf(6.0f, t, 6.0f);
            const float hs  = v * __builtin_amdgcn_rcpf(den);
            const float r   = fminf(1.0f, fmaxf(-1.0f, hs - bv));
            out[(obase + oh) * OWW + ow] = r;
        }
    }
}

extern "C" void kernel_launch(void* const* d_in, const int* in_sizes, int n_in,
                              void* d_out, int out_size, void* d_ws, size_t ws_size,
                              hipStream_t stream) {
    const float* x    = (const float*)d_in[0];
    const float* w    = (const float*)d_in[1];
    const float* bias = (const float*)d_in[2];
    float* out        = (float*)d_out;
    float* wt         = (float*)d_ws;     // 1296 floats = 5.2 KB scratch

    wprep_kernel<<<dim3(6), dim3(256), 0, stream>>>(w, wt);

    dim3 grid(4, ODD, NB);   // 4 i-chunks (8 i-values each) x od x batch
    dim3 block(256);
    convt_lse_kernel<<<grid, block, 0, stream>>>(x, wt, bias, out);
}

// Round 12
// 87.441 us; speedup vs baseline: 1.4165x; 1.1266x over previous
//
#include <hip/hip_runtime.h>

#define IC 3
#define OCH 16
#define IDD 16
#define IHH 32
#define IWW 32
#define ODD 31
#define OHH 63
#define OWW 63
#define NB 32

typedef float f2 __attribute__((ext_vector_type(2)));
typedef float f4 __attribute__((ext_vector_type(4)));

#define LOG2E 1.44269504088896340736f
#define LN2   0.69314718055994530942f

static __device__ __forceinline__ f2 fma2(f2 a, f2 b, f2 c) {
    return __builtin_elementwise_fma(a, b, c);   // -> v_pk_fma_f32
}

// ---- kernel A: one-time weight transpose into workspace -------------------------
// wt[((ic*3+kd)*9 + kh*3+kw)*16 + oc] = w[(ic*16+oc)*27 + kd*9+kh*3+kw] * log2(e)
__global__ void wprep_kernel(const float* __restrict__ w, float* __restrict__ wt) {
    int idx = threadIdx.x + blockIdx.x * 256;
    if (idx < IC * 27 * OCH) {
        int ic   = idx / (27 * OCH);
        int rem  = idx - ic * (27 * OCH);
        int kpos = rem >> 4;
        int oc   = rem & 15;
        wt[idx] = w[(ic * OCH + oc) * 27 + kpos] * LOG2E;
    }
}

// ---- main kernel ----------------------------------------------------------------
// Fused ConvTranspose3d(3->16,k3,s2,p1) + channel-LSE + x*sigmoid(x+3)/6 - bias, clip [-1,1].
// Round-8 base (no LDS, no barrier, wave-uniform global weight f4s, packed-f2 FMAs).
// NEW: each thread computes an od-PAIR (2t then 2t+1) in two time-SEQUENTIAL phases that
// reuse ONE function-scope acc (re-initialized by phase B's first-taps -> live ranges split).
// Halves total wave count 15872 -> 8192 (the one untested lever: R6 held waves constant and
// was flat). Scratch-trigger avoidance: macro-only acc access (R5 lesson), no interleaved
// dual acc (R2 lesson), phase B reloads plane-t x fresh from L1 instead of keeping it live.
__global__ __launch_bounds__(256, 3) void convt_lse_kernel(
    const float* __restrict__ x, const float* __restrict__ wt,
    const float* __restrict__ bias, float* __restrict__ out)
{
    const int j = threadIdx.x & 31;                       // ow pair: ow = 2j, 2j+1
    const int i = (threadIdx.x >> 5) + (blockIdx.x << 3); // oh pair: oh = 2i, 2i+1
    const int t = blockIdx.y;                             // od pair: od = 2t, 2t+1
    const int b = blockIdx.z;

    const int ih0 = i;
    const int ih1 = min(i + 1, IHH - 1);   // clamp: feeds only non-stored oh=63
    const int iw0 = j;
    const int iw1 = min(j + 1, IWW - 1);   // clamp: feeds only non-stored ow=63

    const float bv = bias[0];

    // acc[p][cp]: p 0=(ee) 1=(eo) 2=(oe) 3=(oo); cp = oc pair. ONE copy, reused by phase B.
    f2 acc[4][8];

// 9 f4 weight loads (wave-uniform addr -> one L1 line broadcast) feeding 18 pk-fma per (ic,q)
#define TAPQ(first, x00, x01, x10, x11, wq)                                           \
    {                                                                                 \
        _Pragma("unroll")                                                             \
        for (int q = 0; q < 4; ++q) {                                                 \
            const f4 W0 = wq[0 * 4 + q], W1 = wq[1 * 4 + q], W2 = wq[2 * 4 + q],      \
                     W3 = wq[3 * 4 + q], W4 = wq[4 * 4 + q], W5 = wq[5 * 4 + q],      \
                     W6 = wq[6 * 4 + q], W7 = wq[7 * 4 + q], W8 = wq[8 * 4 + q];      \
            _Pragma("unroll")                                                         \
            for (int h = 0; h < 2; ++h) {                                             \
                const int cp = 2 * q + h;                                             \
                const f2 w0 = {W0[2*h], W0[2*h+1]}, w1 = {W1[2*h], W1[2*h+1]},        \
                         w2 = {W2[2*h], W2[2*h+1]}, w3 = {W3[2*h], W3[2*h+1]},        \
                         w4 = {W4[2*h], W4[2*h+1]}, w5 = {W5[2*h], W5[2*h+1]},        \
                         w6 = {W6[2*h], W6[2*h+1]}, w7 = {W7[2*h], W7[2*h+1]},        \
                         w8 = {W8[2*h], W8[2*h+1]};                                   \
                if (first) {                                                          \
                    acc[3][cp] = x11 * w0;                                            \
                    acc[2][cp] = x10 * w1;                                            \
                    acc[1][cp] = x01 * w3;                                            \
                    acc[0][cp] = x00 * w4;                                            \
                } else {                                                              \
                    acc[3][cp] = fma2(x11, w0, acc[3][cp]);                           \
                    acc[2][cp] = fma2(x10, w1, acc[2][cp]);                           \
                    acc[1][cp] = fma2(x01, w3, acc[1][cp]);                           \
                    acc[0][cp] = fma2(x00, w4, acc[0][cp]);                           \
                }                                                                     \
                acc[3][cp] = fma2(x10, w2, acc[3][cp]);                               \
                acc[1][cp] = fma2(x00, w5, acc[1][cp]);                               \
                acc[3][cp] = fma2(x01, w6, acc[3][cp]);                               \
                acc[2][cp] = fma2(x00, w7, acc[2][cp]);                               \
                acc[3][cp] = fma2(x00, w8, acc[3][cp]);                               \
            }                                                                         \
        }                                                                             \
    }

// One kd-plane over all ic, x taken from array X (compile-time indexed)
#define DO_TAP(kd, X, first)                                                          \
    {                                                                                 \
        _Pragma("unroll")                                                             \
        for (int ic = 0; ic < IC; ++ic) {                                             \
            const f2 x00 = {X[ic][0], X[ic][0]};                                      \
            const f2 x01 = {X[ic][1], X[ic][1]};                                      \
            const f2 x10 = {X[ic][2], X[ic][2]};                                      \
            const f2 x11 = {X[ic][3], X[ic][3]};                                      \
            const f4* __restrict__ wq = (const f4*)(wt + (ic * 3 + (kd)) * 9 * OCH);  \
            TAPQ((first) && ic == 0, x00, x01, x10, x11, wq)                          \
        }                                                                             \
    }

// Load one x plane (depth id) into array X
#define LOAD_X(X, id)                                                                 \
    {                                                                                 \
        _Pragma("unroll")                                                             \
        for (int ic = 0; ic < IC; ++ic) {                                             \
            const float* __restrict__ xp = x + (((b * IC + ic) * IDD + (id)) << 10);  \
            X[ic][0] = xp[ih0 * IWW + iw0];                                           \
            X[ic][1] = xp[ih0 * IWW + iw1];                                           \
            X[ic][2] = xp[ih1 * IWW + iw0];                                           \
            X[ic][3] = xp[ih1 * IWW + iw1];                                           \
        }                                                                             \
    }

// Epilogue for output plane odv (reads function-scope acc directly; textual, no refs)
#define FINISH(odv)                                                                   \
    {                                                                                 \
        const int oh0   = 2 * i;                                                      \
        const int ow0   = 2 * j;                                                      \
        const int obase = (b * ODD + (odv)) * OHH;                                    \
        _Pragma("unroll")                                                             \
        for (int p = 0; p < 4; ++p) {                                                 \
            const int oh = oh0 + (p >> 1);                                            \
            const int ow = ow0 + (p & 1);                                             \
            if (oh < OHH && ow < OWW) {                                               \
                f2 sa = {0.0f, 0.0f}, sb = {0.0f, 0.0f};                              \
                _Pragma("unroll")                                                     \
                for (int cp = 0; cp < 8; cp += 2) {                                   \
                    f2 ea, eb;                                                        \
                    ea.x = __builtin_amdgcn_exp2f(acc[p][cp].x);                      \
                    ea.y = __builtin_amdgcn_exp2f(acc[p][cp].y);                      \
                    eb.x = __builtin_amdgcn_exp2f(acc[p][cp + 1].x);                  \
                    eb.y = __builtin_amdgcn_exp2f(acc[p][cp + 1].y);                  \
                    sa += ea;                                                         \
                    sb += eb;                                                         \
                }                                                                     \
                const f2 st   = sa + sb;                                              \
                const float S = st.x + st.y;                                          \
                const float v = LN2 * __builtin_amdgcn_logf(S);                       \
                const float e = __builtin_amdgcn_exp2f(fmaf(-LOG2E, v, -3.0f * LOG2E)); \
                const float hs = v * __builtin_amdgcn_rcpf(fmaf(6.0f, e, 6.0f));      \
                const float r  = fminf(1.0f, fmaxf(-1.0f, hs - bv));                  \
                out[(obase + oh) * OWW + ow] = r;                                     \
            }                                                                         \
        }                                                                             \
    }

    // ---- phase A: od = 2t (even), kd=1 @ plane t
    {
        float xa[IC][4];
        LOAD_X(xa, t)
        DO_TAP(1, xa, true)
        FINISH(2 * t)
    }

    __builtin_amdgcn_sched_barrier(0);   // hard seam: no cross-phase live-range merge

    // ---- phase B: od = 2t+1 (odd), kd=0 @ plane t+1, kd=2 @ plane t (reloaded, L1-hot)
    if (t < 15) {
        float xb[IC][4], xc[IC][4];
        LOAD_X(xb, t + 1)
        LOAD_X(xc, t)
        DO_TAP(0, xb, true)      // first=true re-initializes acc: phase-A acc is dead here
        DO_TAP(2, xc, false)
        FINISH(2 * t + 1)
    }
}

extern "C" void kernel_launch(void* const* d_in, const int* in_sizes, int n_in,
                              void* d_out, int out_size, void* d_ws, size_t ws_size,
                              hipStream_t stream) {
    const float* x    = (const float*)d_in[0];
    const float* w    = (const float*)d_in[1];
    const float* bias = (const float*)d_in[2];
    float* out        = (float*)d_out;
    float* wt         = (float*)d_ws;     // 1296 floats = 5.2 KB scratch

    wprep_kernel<<<dim3(6), dim3(256), 0, stream>>>(w, wt);

    dim3 grid(4, 16, NB);   // 4 i-chunks x od-pairs x batch = 2048 blocks, 8192 waves
    dim3 block(256);
    convt_lse_kernel<<<grid, block, 0, stream>>>(x, wt, bias, out);
}